// Round 5
// baseline (832.496 us; speedup 1.0000x reference)
//
#include <hip/hip_runtime.h>
#include <hip/hip_bf16.h>
#include <stdint.h>

// Problem constants: B=32, T=4096, Dq=Dk=512, A=512
#define DQ 512
#define DK 512
#define NA 512
#define TT 4096
#define NBATCH 32
#define M_TOTAL (NBATCH * TT)

#define BM 64
#define BK 32
#define KITERS (DK / BK)   // 16

typedef __attribute__((ext_vector_type(8))) short bf16x8;   // MFMA A/B frag (4 VGPRs)
typedef __attribute__((ext_vector_type(4))) float f32x4;    // MFMA C/D frag

// async global->LDS, 16B/lane. LDS dst = wave-uniform base + lane*16.
__device__ __forceinline__ void gll16(const void* g, void* l) {
  __builtin_amdgcn_global_load_lds(
      (const __attribute__((address_space(1))) uint32_t*)g,
      (__attribute__((address_space(3))) uint32_t*)l, 16, 0, 0);
}

// fp32 pair -> packed bf16 (round-half-up): 2 adds + v_perm_b32.
__device__ __forceinline__ uint32_t pack2bf16(float a, float b) {
  uint32_t ua = __float_as_uint(a) + 0x8000u;
  uint32_t ub = __float_as_uint(b) + 0x8000u;
  return __builtin_amdgcn_perm(ub, ua, 0x07060302);   // {ub.hi16 : ua.hi16}
}

// two float4 -> one bf16x8 A/B fragment
__device__ __forceinline__ bf16x8 pack8(float4 lo, float4 hi) {
  union { uint32_t u[4]; bf16x8 v; } r;
  r.u[0] = pack2bf16(lo.x, lo.y);
  r.u[1] = pack2bf16(lo.z, lo.w);
  r.u[2] = pack2bf16(hi.x, hi.y);
  r.u[3] = pack2bf16(hi.z, hi.w);
  return r.v;
}

// fast tanh: 1 - 2/(e^{2x}+1); correct limits at +/-inf
__device__ __forceinline__ float fast_tanh(float x) {
  float e = __expf(2.0f * x);
  return 1.0f - 2.0f * __builtin_amdgcn_rcpf(e + 1.0f);
}

// --- merged prep (W-transpose -> K-blocked tiled bf16) + qpb (exact fp32) ---
// Tiled layout: WkTt[(d>>5)*16384 + n*32 + (d&31)] = bf16(W[512+d][n])
__global__ void prep_kernel(const float* __restrict__ W,
                            const float* __restrict__ q,
                            const float* __restrict__ bias,
                            uint16_t* __restrict__ WkTt,
                            float* __restrict__ qpb) {
  const int tid = threadIdx.x;
  if (blockIdx.x < 64) {
    __shared__ uint16_t T[64][65];
    const int d0 = (blockIdx.x & 7) * 64;
    const int a0 = (blockIdx.x >> 3) * 64;
#pragma unroll
    for (int j = 0; j < 16; ++j) {
      int dd = j * 4 + (tid >> 6);
      int aa = tid & 63;   // coalesced read
      uint32_t u = __float_as_uint(W[(size_t)(DQ + d0 + dd) * NA + a0 + aa]) + 0x8000u;
      T[dd][aa] = (uint16_t)(u >> 16);
    }
    __syncthreads();
#pragma unroll
    for (int j = 0; j < 8; ++j) {
      int aa = j * 8 + (tid >> 5);
      int n  = a0 + aa;
      int dp = (tid & 31) * 2;
      int d  = d0 + dp;
      uint32_t val = (uint32_t)T[dp][aa] | ((uint32_t)T[dp + 1][aa] << 16);
      *(uint32_t*)(WkTt + (size_t)(d >> 5) * 16384 + n * 32 + (d & 31)) = val;
    }
  } else {
    const int bb = blockIdx.x - 64;
    const int b  = bb >> 1;
    const int a  = (bb & 1) * 256 + tid;
    const float* qr = q + b * DQ;   // wave-uniform -> scalar loads
    float acc = bias[a];
#pragma unroll 8
    for (int d = 0; d < DQ; ++d)
      acc = fmaf(qr[d], W[(size_t)d * NA + a], acc);
    qpb[b * NA + a] = acc;
  }
}

// --- fused: 64x512 kp GEMM. B via dbuf LDS-DMA; A direct global->reg frags
//     (kills the 8x-redundant A LDS reads that made R4 LDS-pipe-bound). ---
__global__ __launch_bounds__(512, 4)
void score_kernel(const float* __restrict__ Kmat,        // fp32 [M_TOTAL, DK]
                  const uint16_t* __restrict__ WkTt,     // tiled bf16 [16][512][32]
                  const float* __restrict__ qpb,         // fp32 [NBATCH, NA]
                  const float* __restrict__ v,           // fp32 [NA]
                  float* __restrict__ out) {             // fp32 [M_TOTAL]
  __shared__ __align__(16) uint16_t Bs[2][NA * BK];      // 2 x 32 KB
  __shared__ float part[8][BM];                          // 2 KB

  const int tid  = threadIdx.x;
  const int lane = tid & 63;
  const int w    = tid >> 6;      // wave 0..7 -> cols w*64 .. w*64+63
  const int r16  = lane & 15;
  const int quad = lane >> 4;
  const int m_tile = blockIdx.x;
  const int sw = quad ^ ((r16 >> 1) & 3);   // B frag-read granule swizzle

  f32x4 acc[4][4];
#pragma unroll
  for (int i = 0; i < 4; ++i)
#pragma unroll
    for (int j = 0; j < 4; ++j) {
      f32x4 z = {0.f, 0.f, 0.f, 0.f};
      acc[i][j] = z;
    }

  // ---- B-DMA per-thread source pointers (4 granule-loads/thread/iter) ----
  const uint16_t* bsrc[4];
#pragma unroll
  for (int j = 0; j < 4; ++j) {
    int s   = j * 512 + w * 64 + lane;          // LDS-linear granule id
    int n   = s >> 2;
    int ksl = s & 3;
    int ks  = ksl ^ ((n >> 1) & 3);             // inverse swizzle at source
    bsrc[j] = WkTt + n * 32 + ks * 8;
  }
  const int bdst_off[4] = { (0 * 512 + w * 64) * 16, (1 * 512 + w * 64) * 16,
                            (2 * 512 + w * 64) * 16, (3 * 512 + w * 64) * 16 };

  // ---- A direct-global fragment pointer: lane needs rows ms*16+r16, k=quad*8..+7.
  // Per iter each row's 32 k-floats are one 128B line; 2x float4 per frag.
  const float* Aptr = Kmat + ((size_t)m_tile * BM + r16) * DK + quad * 8;

  // ---- preloop: B(0) DMA; load+convert A(0) ----
#pragma unroll
  for (int j = 0; j < 4; ++j) {
    gll16((const void*)bsrc[j], (void*)((char*)Bs[0] + bdst_off[j]));
    bsrc[j] += 16384;
  }
  bf16x8 af[4];
#pragma unroll
  for (int ms = 0; ms < 4; ++ms) {
    const float* p = Aptr + (size_t)ms * 16 * DK;
    af[ms] = pack8(*(const float4*)p, *(const float4*)(p + 4));
  }

#pragma unroll 2
  for (int it = 0; it < KITERS; ++it) {
    const int cur = it & 1, nxt = cur ^ 1;

    __syncthreads();   // B(it) DMA drained into Bs[cur]; Bs[nxt] free

    float4 lo[4], hi[4];
    if (it + 1 < KITERS) {
      // B(it+1) DMA -> Bs[nxt]: drains at NEXT barrier, covered by MFMA phase
#pragma unroll
      for (int j = 0; j < 4; ++j) {
        gll16((const void*)bsrc[j], (void*)((char*)Bs[nxt] + bdst_off[j]));
        bsrc[j] += 16384;
      }
      // A(it+1) prefetch (fp32 in flight across the MFMA phase)
#pragma unroll
      for (int ms = 0; ms < 4; ++ms) {
        const float* p = Aptr + (size_t)ms * 16 * DK + (it + 1) * BK;
        lo[ms] = *(const float4*)p;
        hi[ms] = *(const float4*)(p + 4);
      }
    }

    // ---- B frag reads (swizzled, 2-way bank aliasing = free) + MFMA ----
    bf16x8 bfr[4];
#pragma unroll
    for (int ns = 0; ns < 4; ++ns)
      bfr[ns] = *(const bf16x8*)((char*)Bs[cur] + (w * 64 + ns * 16 + r16) * 64 + sw * 16);
#pragma unroll
    for (int ms = 0; ms < 4; ++ms)
#pragma unroll
      for (int ns = 0; ns < 4; ++ns)
        acc[ms][ns] = __builtin_amdgcn_mfma_f32_16x16x32_bf16(
            af[ms], bfr[ns], acc[ms][ns], 0, 0, 0);

    // convert A(it+1) after the MFMA block (frees fp32 transients before loop-back)
    if (it + 1 < KITERS) {
#pragma unroll
      for (int ms = 0; ms < 4; ++ms)
        af[ms] = pack8(lo[ms], hi[ms]);
    }
  }

  // ---- epilogue: tanh(acc + qpb) * v, reduce 512 cols -> 64 row sums ----
  const size_t row0 = (size_t)m_tile * BM;
  const int b_idx = m_tile >> 6;              // 4096 rows/batch, 64 | 4096

  float vv[4], qv[4];
#pragma unroll
  for (int ns = 0; ns < 4; ++ns) {
    int a = w * 64 + ns * 16 + r16;           // C/D col = lane&15
    vv[ns] = v[a];
    qv[ns] = qpb[b_idx * NA + a];
  }

#pragma unroll
  for (int ms = 0; ms < 4; ++ms) {
#pragma unroll
    for (int reg = 0; reg < 4; ++reg) {
      float s = 0.f;
#pragma unroll
      for (int ns = 0; ns < 4; ++ns) {
        float x = acc[ms][ns][reg] + qv[ns];
        s = fmaf(fast_tanh(x), vv[ns], s);
      }
      // C/D row = quad*4+reg; its 16 cols live in this quad's lanes
      s += __shfl_xor(s, 1);
      s += __shfl_xor(s, 2);
      s += __shfl_xor(s, 4);
      s += __shfl_xor(s, 8);
      if (r16 == 0) part[w][ms * 16 + quad * 4 + reg] = s;
    }
  }
  __syncthreads();
  if (tid < BM) {
    float s = 0.f;
#pragma unroll
    for (int ww = 0; ww < 8; ++ww) s += part[ww][tid];
    out[row0 + tid] = s;
  }
}

extern "C" void kernel_launch(void* const* d_in, const int* in_sizes, int n_in,
                              void* d_out, int out_size, void* d_ws, size_t ws_size,
                              hipStream_t stream) {
  const float* q = (const float*)d_in[0];
  const float* k = (const float*)d_in[1];
  const float* W = (const float*)d_in[2];
  const float* b = (const float*)d_in[3];
  const float* v = (const float*)d_in[4];
  float* out = (float*)d_out;

  // ws: [0,64KB) qpb fp32; [64KB,576KB) WkTt bf16 (tiled)
  float* qpb = (float*)d_ws;
  uint16_t* WkTt = (uint16_t*)((char*)d_ws + 65536);

  prep_kernel<<<128, 256, 0, stream>>>(W, q, b, WkTt, qpb);
  score_kernel<<<M_TOTAL / BM, 512, 0, stream>>>(k, WkTt, qpb, v, out);
}